// Round 15
// baseline (545.557 us; speedup 1.0000x reference)
//
#include <hip/hip_runtime.h>
#include <stdint.h>

typedef float f32x4 __attribute__((ext_vector_type(4)));
typedef short s16x8 __attribute__((ext_vector_type(8)));
typedef unsigned u32x4 __attribute__((ext_vector_type(4)));

#define B_SZ 256
#define A_RG 196
#define DVD  2048
#define RNN  1024
#define H_SZ 512
#define M_TOT (B_SZ * A_RG)   // 50176
#define NKT  (DVD / 32)       // 64 K-tiles

__device__ __forceinline__ unsigned short f2bf(float f) {
    unsigned u = __builtin_bit_cast(unsigned, f);
    u = u + 0x7FFFu + ((u >> 16) & 1u);   // RNE
    return (unsigned short)(u >> 16);
}

__device__ __forceinline__ unsigned cvt2(float a, float b) {
    unsigned r;
    asm("v_cvt_pk_bf16_f32 %0, %1, %2" : "=v"(r) : "v"(a), "v"(b));
    return r;
}

// ---------------------------------------------------------------------------
// Kernel 1: W_v [2048,512] fp32 -> Wt4 bf16 in MFMA-B-fragment order
// (R11/R13-verified): byte offset of frag f, tile kt = kt*32768 + f*1024
// + lane*16 (lane = g*16+lr; elems k = kt*32 + g*8 .. +7 of col f*16+lr).
// ---------------------------------------------------------------------------
__global__ __launch_bounds__(256) void k_prepW(const float* __restrict__ Wv,
                                               unsigned short* __restrict__ Wt4) {
    __shared__ float tile[64][65];
    int kb = blockIdx.x >> 3, ct = blockIdx.x & 7;
    int k0 = kb * 64, c0 = ct * 64;
    int t = threadIdx.x;
    int cl = t & 63, rq = t >> 6;
#pragma unroll
    for (int i = 0; i < 16; ++i) {
        int r = rq * 16 + i;
        tile[r][cl] = Wv[(size_t)(k0 + r) * H_SZ + c0 + cl];
    }
    __syncthreads();
    int kl = t & 63;
#pragma unroll
    for (int i = 0; i < 16; ++i) {
        int cr = rq * 16 + i;
        int col = c0 + cr;
        int k = k0 + kl;
        int f = col >> 4, lr = col & 15;
        int kt = k >> 5, g = (k >> 3) & 3, e = k & 7;
        size_t dst = ((size_t)(kt * 32 + f) * 64 + g * 16 + lr) * 8 + e;
        Wt4[dst] = f2bf(tile[kl][cr]);
    }
}

// ---------------------------------------------------------------------------
// Kernel 2: base[b,h] = h_att[b]@W_ha + prev_h2[b]@W_hv + b_ha + b_hv + b_v
// ---------------------------------------------------------------------------
__global__ __launch_bounds__(256) void k_base(const float* __restrict__ h_att,
                                              const float* __restrict__ prev_h2,
                                              const float* __restrict__ W_ha,
                                              const float* __restrict__ b_ha,
                                              const float* __restrict__ W_hv,
                                              const float* __restrict__ b_hv,
                                              const float* __restrict__ b_v,
                                              float* __restrict__ base_g) {
    __shared__ float ha_s[4][RNN];
    __shared__ float pv_s[4][RNN];
    int bg = blockIdx.x >> 2, hg = blockIdx.x & 3;
    int t = threadIdx.x;
#pragma unroll
    for (int i = 0; i < 16; ++i) {
        int idx = i * 256 + t;
        int bl = idx >> 10, k = idx & 1023;
        ha_s[bl][k] = h_att[(size_t)(bg * 4 + bl) * RNN + k];
        pv_s[bl][k] = prev_h2[(size_t)(bg * 4 + bl) * RNN + k];
    }
    __syncthreads();
    int h = hg * 128 + (t & 127);
    int br = t >> 7;
    float aA0 = 0, aA1 = 0, aV0 = 0, aV1 = 0;
#pragma unroll 4
    for (int k = 0; k < RNN; ++k) {
        float w1 = W_ha[(size_t)k * H_SZ + h];
        float w2 = W_hv[(size_t)k * H_SZ + h];
        aA0 = fmaf(ha_s[br * 2][k],     w1, aA0);
        aA1 = fmaf(ha_s[br * 2 + 1][k], w1, aA1);
        aV0 = fmaf(pv_s[br * 2][k],     w2, aV0);
        aV1 = fmaf(pv_s[br * 2 + 1][k], w2, aV1);
    }
    float bias = b_ha[h] + b_hv[h] + b_v[h];
    base_g[(size_t)(bg * 4 + br * 2) * H_SZ + h]     = aA0 + aV0 + bias;
    base_g[(size_t)(bg * 4 + br * 2 + 1) * H_SZ + h] = aA1 + aV1 + bias;
}

// ---------------------------------------------------------------------------
// Kernel 3 (fused, R15): one block per b; row-tiles {128, 68}. GEMM inner
// loop is BARRIER-FREE and LDS-FREE: per-wave register-direct A (lane loads
// its own MFMA fragment bytes straight from imgs; same-wm waves' duplicate
// reads are absorbed by L1/L2 inside the CU/XCD -> HBM FETCH stays 1x) and
// register-direct B from L2-hot fragment-packed Wt4. 2-deep A prefetch,
// B WAR-reload, compiler-counted vmcnt, setprio on MFMA clusters. Barriers
// only at the softmax handoff (2 per row-tile). Score epilogue -> online
// softmax -> V accumulate as R13 (verified).
// ---------------------------------------------------------------------------
__global__ __launch_bounds__(512, 2) void k_fused(const float* __restrict__ imgs,
                                                  const unsigned short* __restrict__ Wt4,
                                                  const float* __restrict__ base_g,
                                                  const float* __restrict__ W_f,
                                                  float* __restrict__ out) {
    __shared__ float att_part[4][128];
    __shared__ float e_s[128];
    __shared__ float scal_r;
    __shared__ float scal_l;

    const int b = blockIdx.x;
    const int t = threadIdx.x;
    const int lane = t & 63, w = t >> 6;
    const int wm = w >> 2, wn = w & 3;
    const int lr = lane & 15, g = lane >> 4;

    const char* imgc = (const char*)imgs;
    const float* imgb = imgs + (size_t)b * A_RG * DVD;
    const char* Bp = (const char*)Wt4 + ((size_t)(wn * 8) * 64 + lane) * 16;

    f32x4 o = {};                       // thread owns out cols t*4 .. t*4+3
    float m_run = -1e30f, l_run = 0.f;  // live in wave 0

    for (int at = 0; at < 2; ++at) {
        const bool last = (at == 1);
        const int m0 = at * 128;

        // ---- per-lane A fragment byte offsets (flat-row clamped: rows past
        //      the very end of imgs repeat row 50175; masked at softmax) ----
        unsigned aoff[4];
#pragma unroll
        for (int mf = 0; mf < 4; ++mf) {
            int flat = b * A_RG + m0 + wm * 64 + mf * 16 + lr;
            flat = min(flat, M_TOT - 1);
            aoff[mf] = (unsigned)flat * (unsigned)(DVD * 4) + (unsigned)(g * 32);
        }

        f32x4 acc[4][8] = {};
        f32x4 rAe[4][2], rAo[4][2];
        s16x8 aF[4], bR[8];

        auto issueA = [&](int kt, f32x4 (&rA)[4][2]) {
            const char* p = imgc + (size_t)kt * 128;
#pragma unroll
            for (int mf = 0; mf < 4; ++mf) {
                rA[mf][0] = *(const f32x4*)(p + aoff[mf]);
                rA[mf][1] = *(const f32x4*)(p + aoff[mf] + 16);
            }
        };
        auto issueB = [&](int kt) {
            const char* p = Bp + (size_t)kt * 32768;
#pragma unroll
            for (int n = 0; n < 8; ++n)
                bR[n] = *(const s16x8*)(p + n * 1024);
        };
        auto cvtA = [&](const f32x4 (&rA)[4][2]) {
#pragma unroll
            for (int mf = 0; mf < 4; ++mf) {
                u32x4 pk;
                pk[0] = cvt2(rA[mf][0][0], rA[mf][0][1]);
                pk[1] = cvt2(rA[mf][0][2], rA[mf][0][3]);
                pk[2] = cvt2(rA[mf][1][0], rA[mf][1][1]);
                pk[3] = cvt2(rA[mf][1][2], rA[mf][1][3]);
                aF[mf] = __builtin_bit_cast(s16x8, pk);
            }
        };
        auto mma = [&]() {
            __builtin_amdgcn_s_setprio(1);
#pragma unroll
            for (int mf = 0; mf < 4; ++mf)
#pragma unroll
                for (int n = 0; n < 8; ++n)
                    acc[mf][n] = __builtin_amdgcn_mfma_f32_16x16x32_bf16(
                        aF[mf], bR[n], acc[mf][n], 0, 0, 0);
            __builtin_amdgcn_s_setprio(0);
        };

        // ---- barrier-free K loop: 2-deep A pipeline, B WAR-reload ----
        issueA(0, rAe);
        issueB(0);
        issueA(1, rAo);
        cvtA(rAe);                       // waits A(0) only (counted vmcnt)
        for (int kt = 0; kt < NKT; kt += 2) {
            if (kt + 2 < NKT) issueA(kt + 2, rAe);   // rAe dead (already cvt'd)
            mma();                                   // tile kt
            if (kt + 1 < NKT) { issueB(kt + 1); cvtA(rAo); }
            if (kt + 3 < NKT) issueA(kt + 3, rAo);
            if (kt + 1 < NKT) mma();                 // tile kt+1
            if (kt + 2 < NKT) { issueB(kt + 2); cvtA(rAe); }
        }

        // ---- score epilogue: att_part[wn][row] over this wave's 128 cols --
        {
            float wfv[8], bs[8];
#pragma unroll
            for (int n = 0; n < 8; ++n) {
                int col = wn * 128 + n * 16 + lr;
                wfv[n] = W_f[col];
                bs[n] = base_g[(size_t)b * H_SZ + col];
            }
#pragma unroll
            for (int mf = 0; mf < 4; ++mf) {
                float pj[4] = {0.f, 0.f, 0.f, 0.f};
#pragma unroll
                for (int n = 0; n < 8; ++n) {
                    float a0 = fmaxf(acc[mf][n][0] + bs[n], 0.f);
                    float a1 = fmaxf(acc[mf][n][1] + bs[n], 0.f);
                    float a2 = fmaxf(acc[mf][n][2] + bs[n], 0.f);
                    float a3 = fmaxf(acc[mf][n][3] + bs[n], 0.f);
                    pj[0] = fmaf(a0, wfv[n], pj[0]);
                    pj[1] = fmaf(a1, wfv[n], pj[1]);
                    pj[2] = fmaf(a2, wfv[n], pj[2]);
                    pj[3] = fmaf(a3, wfv[n], pj[3]);
                }
#pragma unroll
                for (int j = 0; j < 4; ++j) {
                    float s = pj[j];
                    s += __shfl_xor(s, 1);
                    s += __shfl_xor(s, 2);
                    s += __shfl_xor(s, 4);
                    s += __shfl_xor(s, 8);
                    if (lr == 0)
                        att_part[wn][wm * 64 + mf * 16 + g * 4 + j] = s;
                }
            }
        }
        __builtin_amdgcn_s_barrier();

        // ---- wave 0: online-softmax state update ----
        if (w == 0) {
            int gr0 = m0 + lane, gr1 = m0 + lane + 64;
            float s0 = (gr0 < A_RG)
                ? (att_part[0][lane] + att_part[1][lane] + att_part[2][lane] + att_part[3][lane])
                : -1e30f;
            float s1 = (gr1 < A_RG)
                ? (att_part[0][lane + 64] + att_part[1][lane + 64] +
                   att_part[2][lane + 64] + att_part[3][lane + 64])
                : -1e30f;
            float mx = fmaxf(s0, s1);
            for (int d = 1; d < 64; d <<= 1) mx = fmaxf(mx, __shfl_xor(mx, d));
            float m_new = fmaxf(m_run, mx);
            float r = __expf(m_run - m_new);
            float e0 = __expf(s0 - m_new);
            float e1 = __expf(s1 - m_new);
            float es = e0 + e1;
            for (int d = 1; d < 64; d <<= 1) es += __shfl_xor(es, d);
            l_run = l_run * r + es;
            m_run = m_new;
            e_s[lane] = e0;
            e_s[lane + 64] = e1;
            if (lane == 0) {
                scal_r = r;
                if (last) scal_l = l_run;
            }
        }
        __builtin_amdgcn_s_barrier();

        // ---- V phase: o = o*r + sum_a e[a] * imgs[b, m0+a, t*4..] ----
        {
            float r = scal_r;
            o[0] *= r; o[1] *= r; o[2] *= r; o[3] *= r;
            const float* vb = imgb + t * 4;
            const int AV = last ? (A_RG - 128) : 128;   // 68 or 128
#pragma unroll 4
            for (int a = 0; a < AV; ++a) {
                float e = e_s[a];
                f32x4 v = *(const f32x4*)(vb + (size_t)(m0 + a) * DVD);
                o[0] = fmaf(e, v[0], o[0]);
                o[1] = fmaf(e, v[1], o[1]);
                o[2] = fmaf(e, v[2], o[2]);
                o[3] = fmaf(e, v[3], o[3]);
            }
        }
        // cross-tile hazards (e_s, att_part reuse) are covered by the next
        // tile's pre-softmax barrier: each wave rewrites att_part only after
        // its own V phase, and wave0 rewrites e_s only after that barrier.
    }

    // ---- finalize: out[b, t*4..] = o / l ----
    float linv = 1.0f / scal_l;
    f32x4 res;
    res[0] = o[0] * linv; res[1] = o[1] * linv;
    res[2] = o[2] * linv; res[3] = o[3] * linv;
    *(f32x4*)(out + (size_t)b * DVD + t * 4) = res;
}

// ---------------------------------------------------------------------------
extern "C" void kernel_launch(void* const* d_in, const int* in_sizes, int n_in,
                              void* d_out, int out_size, void* d_ws, size_t ws_size,
                              hipStream_t stream) {
    const float* h_att   = (const float*)d_in[0];
    const float* prev_h2 = (const float*)d_in[1];
    const float* imgs    = (const float*)d_in[2];
    const float* W_v     = (const float*)d_in[3];
    const float* b_v     = (const float*)d_in[4];
    const float* W_ha    = (const float*)d_in[5];
    const float* b_ha    = (const float*)d_in[6];
    const float* W_hv    = (const float*)d_in[7];
    const float* b_hv    = (const float*)d_in[8];
    const float* W_f     = (const float*)d_in[9];
    // d_in[10] = b_f: softmax-invariant additive constant -> unused

    // ws layout: [0,2MB) Wt4 bf16 fragment-packed; [2MB,+512KB) base fp32
    unsigned short* Wt4 = (unsigned short*)d_ws;
    float* base_g = (float*)((char*)d_ws + (size_t)DVD * H_SZ * 2);
    float* out = (float*)d_out;

    hipLaunchKernelGGL(k_prepW, dim3(256), dim3(256), 0, stream, W_v, Wt4);
    hipLaunchKernelGGL(k_base, dim3(256), dim3(256), 0, stream,
                       h_att, prev_h2, W_ha, b_ha, W_hv, b_hv, b_v, base_g);
    hipLaunchKernelGGL(k_fused, dim3(B_SZ), dim3(512), 0, stream,
                       imgs, Wt4, base_g, W_f, out);
}

// Round 16
// 334.546 us; speedup vs baseline: 1.6307x; 1.6307x over previous
//
#include <hip/hip_runtime.h>
#include <stdint.h>

typedef float f32x4 __attribute__((ext_vector_type(4)));
typedef short s16x8 __attribute__((ext_vector_type(8)));
typedef unsigned u32x2 __attribute__((ext_vector_type(2)));

#define B_SZ 256
#define A_RG 196
#define DVD  2048
#define RNN  1024
#define H_SZ 512
#define NKT  (DVD / 32)       // 64 K-tiles

__device__ __forceinline__ unsigned short f2bf(float f) {
    unsigned u = __builtin_bit_cast(unsigned, f);
    u = u + 0x7FFFu + ((u >> 16) & 1u);   // RNE
    return (unsigned short)(u >> 16);
}

__device__ __forceinline__ unsigned cvt2(float a, float b) {
    unsigned r;
    asm("v_cvt_pk_bf16_f32 %0, %1, %2" : "=v"(r) : "v"(a), "v"(b));
    return r;
}

// ---------------------------------------------------------------------------
// Kernel 1: W_v [2048,512] fp32 -> Wt4 bf16 in MFMA-B-fragment order
// (R11/R13-verified): ushort idx = ((kt*32 + f)*64 + g*16 + lr)*8 + e,
// f=col>>4, lr=col&15, kt=k>>5, g=(k>>3)&3, e=k&7.
// ---------------------------------------------------------------------------
__global__ __launch_bounds__(256) void k_prepW(const float* __restrict__ Wv,
                                               unsigned short* __restrict__ Wt4) {
    __shared__ float tile[64][65];
    int kb = blockIdx.x >> 3, ct = blockIdx.x & 7;
    int k0 = kb * 64, c0 = ct * 64;
    int t = threadIdx.x;
    int cl = t & 63, rq = t >> 6;
#pragma unroll
    for (int i = 0; i < 16; ++i) {
        int r = rq * 16 + i;
        tile[r][cl] = Wv[(size_t)(k0 + r) * H_SZ + c0 + cl];
    }
    __syncthreads();
    int kl = t & 63;
#pragma unroll
    for (int i = 0; i < 16; ++i) {
        int cr = rq * 16 + i;
        int col = c0 + cr;
        int k = k0 + kl;
        int f = col >> 4, lr = col & 15;
        int kt = k >> 5, g = (k >> 3) & 3, e = k & 7;
        size_t dst = ((size_t)(kt * 32 + f) * 64 + g * 16 + lr) * 8 + e;
        Wt4[dst] = f2bf(tile[kl][cr]);
    }
}

// ---------------------------------------------------------------------------
// Kernel 2: base[b,h] = h_att[b]@W_ha + prev_h2[b]@W_hv + b_ha + b_hv + b_v
// ---------------------------------------------------------------------------
__global__ __launch_bounds__(256) void k_base(const float* __restrict__ h_att,
                                              const float* __restrict__ prev_h2,
                                              const float* __restrict__ W_ha,
                                              const float* __restrict__ b_ha,
                                              const float* __restrict__ W_hv,
                                              const float* __restrict__ b_hv,
                                              const float* __restrict__ b_v,
                                              float* __restrict__ base_g) {
    __shared__ float ha_s[4][RNN];
    __shared__ float pv_s[4][RNN];
    int bg = blockIdx.x >> 2, hg = blockIdx.x & 3;
    int t = threadIdx.x;
#pragma unroll
    for (int i = 0; i < 16; ++i) {
        int idx = i * 256 + t;
        int bl = idx >> 10, k = idx & 1023;
        ha_s[bl][k] = h_att[(size_t)(bg * 4 + bl) * RNN + k];
        pv_s[bl][k] = prev_h2[(size_t)(bg * 4 + bl) * RNN + k];
    }
    __syncthreads();
    int h = hg * 128 + (t & 127);
    int br = t >> 7;
    float aA0 = 0, aA1 = 0, aV0 = 0, aV1 = 0;
#pragma unroll 4
    for (int k = 0; k < RNN; ++k) {
        float w1 = W_ha[(size_t)k * H_SZ + h];
        float w2 = W_hv[(size_t)k * H_SZ + h];
        aA0 = fmaf(ha_s[br * 2][k],     w1, aA0);
        aA1 = fmaf(ha_s[br * 2 + 1][k], w1, aA1);
        aV0 = fmaf(pv_s[br * 2][k],     w2, aV0);
        aV1 = fmaf(pv_s[br * 2 + 1][k], w2, aV1);
    }
    float bias = b_ha[h] + b_hv[h] + b_v[h];
    base_g[(size_t)(bg * 4 + br * 2) * H_SZ + h]     = aA0 + aV0 + bias;
    base_g[(size_t)(bg * 4 + br * 2 + 1) * H_SZ + h] = aA1 + aV1 + bias;
}

// ---------------------------------------------------------------------------
// Kernel 3 (fused, R16): R13 structure at HALF the register footprint.
// 1024 thr = 16 waves (2M x 8N), wave tile 64x64, acc[4][4] = 64 AGPR ->
// ~115-128 unified regs -> 4 waves/SIMD (16 waves/CU), doubling the
// wave-level latency hiding that R13 lacked. A: LDS dbuf (1 f32x4/thread
// staging, XOR slot), B: register-direct 4 frags w/ imm offsets, 1 barrier
// per kstep, then score -> online softmax -> V accumulate (R13-verified).
// Tile1 is uniform (no mf4 branch): extra rows clamp-duplicated and masked.
// ---------------------------------------------------------------------------
__global__ __launch_bounds__(1024, 4) void k_fused(const float* __restrict__ imgs,
                                                   const unsigned short* __restrict__ Wt4,
                                                   const float* __restrict__ base_g,
                                                   const float* __restrict__ W_f,
                                                   float* __restrict__ out) {
    __shared__ __align__(16) short A_s[2][128 * 32];   // 2 x 8 KB
    __shared__ float att_part[8][128];
    __shared__ float e_s[128];
    __shared__ float scal_r;
    __shared__ float scal_l;

    const int b = blockIdx.x;
    const int t = threadIdx.x;
    const int lane = t & 63, w = t >> 6;
    const int wm = w >> 3, wn = w & 7;           // 2M x 8N wave grid
    const int lr = lane & 15, g = lane >> 4;

    const float* imgb = imgs + (size_t)b * A_RG * DVD;
    const char* Bp = (const char*)Wt4 + ((size_t)(wn * 4) * 64 + lane) * 16;

    f32x4 o2;                           // thread owns out cols 2t, 2t+1
    float o0 = 0.f, o1 = 0.f;
    float m_run = -1e30f, l_run = 0.f;  // live in wave 0
    (void)o2;

    // ---- A staging map: thread -> local row t>>3, chunk t&7 (4 floats) ----
    const int arow = t >> 3, ac = t & 7;
    const unsigned awr = (unsigned)(arow * 64 +
        ((((ac >> 1) ^ ((arow ^ (arow >> 2)) & 3)) << 4) | ((ac & 1) << 3)));

    // ---- A fragment read addresses ----
    unsigned ard[4];
#pragma unroll
    for (int mf = 0; mf < 4; ++mf) {
        int r = wm * 64 + mf * 16 + lr;
        ard[mf] = (unsigned)(r * 64 + ((g ^ ((r ^ (r >> 2)) & 3)) << 4));
    }

    for (int at = 0; at < 2; ++at) {
        const bool last = (at == 1);
        const int m0 = at * 128;

        const float* Ag = imgb + (size_t)min(m0 + arow, A_RG - 1) * DVD + ac * 4;

        f32x4 acc[4][4] = {};
        f32x4 rA;
        s16x8 aF[4], bR[4];

        auto ldA = [&](int kt) {
            rA = *(const f32x4*)(Ag + (size_t)kt * 32);
        };
        auto wrA = [&](int buf) {
            u32x2 pk;
            pk[0] = cvt2(rA[0], rA[1]);
            pk[1] = cvt2(rA[2], rA[3]);
            *(u32x2*)((char*)A_s[buf] + awr) = pk;
        };
        auto ldB = [&](int kt) {
            const char* p = Bp + (size_t)kt * 32768;
#pragma unroll
            for (int n = 0; n < 4; ++n)
                bR[n] = *(const s16x8*)(p + n * 1024);
        };

        // ---- prologue: B(0), A(0)->LDS buf0 ----
        ldB(0);
        ldA(0);
        wrA(0);                          // waits rA
        asm volatile("s_waitcnt lgkmcnt(0)" ::: "memory");
        __builtin_amdgcn_sched_barrier(0);
        __builtin_amdgcn_s_barrier();

        // ---- K loop: 1 barrier/kstep (R13-proven) ----
        for (int kt = 0; kt < NKT; ++kt) {
            if (kt + 1 < NKT) ldA(kt + 1);           // HBM, lands by wrA below
            const char* Ac = (const char*)A_s[kt & 1];
#pragma unroll
            for (int mf = 0; mf < 4; ++mf)
                aF[mf] = *(const s16x8*)(Ac + ard[mf]);
            __builtin_amdgcn_s_setprio(1);
#pragma unroll
            for (int mf = 0; mf < 4; ++mf)
#pragma unroll
                for (int n = 0; n < 4; ++n)
                    acc[mf][n] = __builtin_amdgcn_mfma_f32_16x16x32_bf16(
                        aF[mf], bR[n], acc[mf][n], 0, 0, 0);
            __builtin_amdgcn_s_setprio(0);
            if (kt + 1 < NKT) {
                ldB(kt + 1);                         // WAR reload, L2
                wrA((kt + 1) & 1);                   // waits rA (auto vmcnt)
                asm volatile("s_waitcnt lgkmcnt(0)" ::: "memory");
                __builtin_amdgcn_sched_barrier(0);
                __builtin_amdgcn_s_barrier();
            }
        }

        // ---- score epilogue: this wave's 64 cols -> att_part[wn][row] ----
        {
            float wfv[4], bs[4];
#pragma unroll
            for (int n = 0; n < 4; ++n) {
                int col = wn * 64 + n * 16 + lr;
                wfv[n] = W_f[col];
                bs[n] = base_g[(size_t)b * H_SZ + col];
            }
#pragma unroll
            for (int mf = 0; mf < 4; ++mf) {
                float pj[4] = {0.f, 0.f, 0.f, 0.f};
#pragma unroll
                for (int n = 0; n < 4; ++n) {
                    float a0 = fmaxf(acc[mf][n][0] + bs[n], 0.f);
                    float a1 = fmaxf(acc[mf][n][1] + bs[n], 0.f);
                    float a2 = fmaxf(acc[mf][n][2] + bs[n], 0.f);
                    float a3 = fmaxf(acc[mf][n][3] + bs[n], 0.f);
                    pj[0] = fmaf(a0, wfv[n], pj[0]);
                    pj[1] = fmaf(a1, wfv[n], pj[1]);
                    pj[2] = fmaf(a2, wfv[n], pj[2]);
                    pj[3] = fmaf(a3, wfv[n], pj[3]);
                }
#pragma unroll
                for (int j = 0; j < 4; ++j) {
                    float s = pj[j];
                    s += __shfl_xor(s, 1);
                    s += __shfl_xor(s, 2);
                    s += __shfl_xor(s, 4);
                    s += __shfl_xor(s, 8);   // 16 lr-lanes of this row
                    if (lr == 0)
                        att_part[wn][wm * 64 + mf * 16 + g * 4 + j] = s;
                }
            }
        }
        __builtin_amdgcn_s_barrier();

        // ---- wave 0: online-softmax state update ----
        if (w == 0) {
            int gr0 = m0 + lane, gr1 = m0 + lane + 64;
            float s0, s1;
            {
                float a = 0.f, c = 0.f;
#pragma unroll
                for (int q = 0; q < 8; ++q) {
                    a += att_part[q][lane];
                    c += att_part[q][lane + 64];
                }
                s0 = (gr0 < A_RG) ? a : -1e30f;
                s1 = (gr1 < A_RG) ? c : -1e30f;
            }
            float mx = fmaxf(s0, s1);
            for (int d = 1; d < 64; d <<= 1) mx = fmaxf(mx, __shfl_xor(mx, d));
            float m_new = fmaxf(m_run, mx);
            float r = __expf(m_run - m_new);
            float e0 = __expf(s0 - m_new);
            float e1 = __expf(s1 - m_new);
            float es = e0 + e1;
            for (int d = 1; d < 64; d <<= 1) es += __shfl_xor(es, d);
            l_run = l_run * r + es;
            m_run = m_new;
            e_s[lane] = e0;
            e_s[lane + 64] = e1;
            if (lane == 0) {
                scal_r = r;
                if (last) scal_l = l_run;
            }
        }
        __builtin_amdgcn_s_barrier();

        // ---- V phase: o = o*r + sum_a e[a] * imgs[b, m0+a, 2t..2t+1] ----
        {
            float r = scal_r;
            o0 *= r; o1 *= r;
            const float2* vb = (const float2*)imgb + t;
            const int AV = last ? (A_RG - 128) : 128;   // 68 or 128
#pragma unroll 4
            for (int a = 0; a < AV; ++a) {
                float e = e_s[a];
                float2 v = vb[(size_t)(m0 + a) * (DVD / 2)];
                o0 = fmaf(e, v.x, o0);
                o1 = fmaf(e, v.y, o1);
            }
        }
        // cross-tile LDS hazards covered by tile1's prologue/kstep barriers
        // (R13-verified pattern).
    }

    // ---- finalize: out[b, 2t..2t+1] = o / l ----
    float linv = 1.0f / scal_l;
    float2 res = make_float2(o0 * linv, o1 * linv);
    ((float2*)(out + (size_t)b * DVD))[t] = res;
}

// ---------------------------------------------------------------------------
extern "C" void kernel_launch(void* const* d_in, const int* in_sizes, int n_in,
                              void* d_out, int out_size, void* d_ws, size_t ws_size,
                              hipStream_t stream) {
    const float* h_att   = (const float*)d_in[0];
    const float* prev_h2 = (const float*)d_in[1];
    const float* imgs    = (const float*)d_in[2];
    const float* W_v     = (const float*)d_in[3];
    const float* b_v     = (const float*)d_in[4];
    const float* W_ha    = (const float*)d_in[5];
    const float* b_ha    = (const float*)d_in[6];
    const float* W_hv    = (const float*)d_in[7];
    const float* b_hv    = (const float*)d_in[8];
    const float* W_f     = (const float*)d_in[9];
    // d_in[10] = b_f: softmax-invariant additive constant -> unused

    // ws layout: [0,2MB) Wt4 bf16 fragment-packed; [2MB,+512KB) base fp32
    unsigned short* Wt4 = (unsigned short*)d_ws;
    float* base_g = (float*)((char*)d_ws + (size_t)DVD * H_SZ * 2);
    float* out = (float*)d_out;

    hipLaunchKernelGGL(k_prepW, dim3(256), dim3(256), 0, stream, W_v, Wt4);
    hipLaunchKernelGGL(k_base, dim3(256), dim3(256), 0, stream,
                       h_att, prev_h2, W_ha, b_ha, W_hv, b_hv, b_v, base_g);
    hipLaunchKernelGGL(k_fused, dim3(B_SZ), dim3(1024), 0, stream,
                       imgs, Wt4, base_g, W_f, out);
}